// Round 5
// baseline (278.985 us; speedup 1.0000x reference)
//
#include <hip/hip_runtime.h>
#include <math.h>

// Problem constants
#define NB 2
#define CIN 16
#define COUT 8
#define DD 96
#define TDIM 256
#define NE 8
#define VOX (DD*DD*DD)          // 884736
#define OUT_ELEMS (NB*COUT*VOX) // 14155776

// ---- workspace layout ----
// [0, XT_BYTES): xt, f16 channels-last [b][vox][ci16] = 32 B / voxel
// [XT_BYTES, +28672): B-fragment table f16 [b][chunk14][lane64][j8]
// then floats at f32-offset 7168: a[b][co]; 7184: d[b][co]
#define XT_BYTES ((size_t)NB * VOX * 32)
#define WS_A_F 7168
#define WS_D_F 7184

// conv LDS tile: 16x*16y*3z outputs, halo -> 18*18*5 voxels
#define LX 18
#define PLANE (LX*LX)           // 324
#define NVX (PLANE*5)           // 1620
#define HALFB (NVX*16)          // 25920 B per ci-half ([vox][8ci] f16)

#define TV 1024                 // transpose voxels per block (4 per thread)
#define NTB (VOX/TV)            // 864

typedef _Float16 f16x8 __attribute__((ext_vector_type(8)));
typedef float f32x4 __attribute__((ext_vector_type(4)));

// ---------------- fused transpose + setup ----------------
// Grid (NTB+1, NB). Blocks (NTB, b) run the setup path for batch b.
// Transpose path: pure register transpose, no LDS, no barrier -> 16
// independent float4 loads in flight per thread (latency hiding).
__global__ __launch_bounds__(256, 4) void transpose_setup(
    const float* __restrict__ x, _Float16* __restrict__ xt,
    const float* __restrict__ text,
    const float* __restrict__ wb,    // [E,COUT,CIN,27]
    const float* __restrict__ bb,    // [E,COUT]
    const float* __restrict__ rw1, const float* __restrict__ rb1,
    const float* __restrict__ rw2, const float* __restrict__ rb2,
    const float* __restrict__ mw1, const float* __restrict__ mb1,
    const float* __restrict__ mw2, const float* __restrict__ mb2,
    float* __restrict__ dout_tail,   // d_out + OUT_ELEMS
    char* __restrict__ tab)          // ws + XT_BYTES
{
    __shared__ float hg[2][64], logits[NE], rwv[NE];   // setup path only (~0.6 KB)
    const int t = threadIdx.x;
    const int b = blockIdx.y;

    if (blockIdx.x == NTB) {
        // ---------- setup path (one block per batch) ----------
        if (t < 128) {
            const int which = t >> 6, j = t & 63;     // 0=router,1=modulator
            const float* w1 = which ? mw1 : rw1;
            const float* b1 = which ? mb1 : rb1;
            float acc = b1[j];
            for (int k = 0; k < TDIM; ++k) acc = fmaf(text[b*TDIM + k], w1[k*64 + j], acc);
            hg[which][j] = (acc >= 0.f) ? acc : 0.1f * acc;
        }
        __syncthreads();
        if (t < NE) {
            float acc = rb2[t];
            for (int k = 0; k < 64; ++k) acc = fmaf(hg[0][k], rw2[k*NE + t], acc);
            logits[t] = acc;
            dout_tail[b*NE + t] = acc;                // router_logits
        }
        __syncthreads();
        if (t < NE) {
            float mx = logits[0];
            for (int k = 1; k < NE; ++k) mx = fmaxf(mx, logits[k]);
            float s = 0.f;
            for (int k = 0; k < NE; ++k) s += expf(logits[k] - mx);
            const float w = expf(logits[t] - mx) / s;
            rwv[t] = w;
            dout_tail[NB*NE + b*NE + t] = w;          // routing_weights
        }
        __syncthreads();
        if (t < COUT) {
            float acc = mb2[t];
            for (int k = 0; k < 64; ++k) acc = fmaf(hg[1][k], mw2[k*COUT + t], acc);
            const float gamma = 1.f / (1.f + expf(-acc));
            const float a = 1.f + gamma;
            float cb = 0.f;
            for (int e = 0; e < NE; ++e) cb = fmaf(rwv[e], bb[e*COUT + t], cb);
            ((float*)tab)[WS_A_F + b*COUT + t] = a;
            ((float*)tab)[WS_D_F + b*COUT + t] = cb * a;
        }
        // bake per-lane MFMA B-fragments for this batch: r = (c*64 + lane)*8 + j
        for (int r = t; r < 14*64*8; r += 256) {
            const int c  = r >> 9;
            const int l  = (r >> 3) & 63;
            const int j  = r & 7;
            const int q  = l >> 4;
            const int n  = l & 15;       // output column = cout (cols 8..15 zero)
            const int p  = q & 1;        // tap parity within chunk
            const int ci = (q >> 1)*8 + j;
            int tap;
            if (c < 9)        tap = (c/3)*9 + (c%3)*3 + p;
            else if (c < 12)  tap = (c-9)*9 + p*3 + 2;
            else if (c == 12) tap = p*9 + 8;
            else              tap = p ? -1 : 26;
            float v = 0.f;
            if (n < 8 && tap >= 0) {
                for (int e = 0; e < NE; ++e)
                    v = fmaf(rwv[e], wb[((e*COUT + n)*CIN + ci)*27 + tap], v);
            }
            ((_Float16*)tab)[b*7168 + r] = (_Float16)v;
        }
        return;
    }

    // ---------- transpose path: x f32 [b][ci][vox] -> xt f16 [b][vox][ci16] ----------
    // Thread owns 4 consecutive voxels. 16 independent float4 loads (one per ci),
    // register repack, 4 x 32 B contiguous stores.
    const int vbase = blockIdx.x * TV + t * 4;
    const float* __restrict__ xb = x + (size_t)b * CIN * VOX + vbase;

    float4 f[CIN];
    #pragma unroll
    for (int ci = 0; ci < CIN; ++ci)
        f[ci] = *(const float4*)(xb + (size_t)ci * VOX);

    _Float16* __restrict__ dst = xt + (size_t)(b*VOX + vbase) * 16;
    #pragma unroll
    for (int k = 0; k < 4; ++k) {
        union { _Float16 h[16]; uint4 u[2]; } o;
        #pragma unroll
        for (int ci = 0; ci < CIN; ++ci) {
            const float* fp = (const float*)&f[ci];
            o.h[ci] = (_Float16)fp[k];
        }
        uint4* __restrict__ d4 = (uint4*)(dst + k*16);
        d4[0] = o.u[0];
        d4[1] = o.u[1];
    }
}

// ---------------- conv: implicit-GEMM f16 MFMA, rolling-plane frag reuse ----------------
// Block = 256 thr (4 waves), tile 16x*16y*3z. Grid = (36, 32, 2).
__global__ __launch_bounds__(256) void conv_mfma(
    const _Float16* __restrict__ xt,   // [b][vox][16] f16
    const char* __restrict__ tab,
    float* __restrict__ out)
{
    __shared__ char lds[2*HALFB];   // [half][vox 1620][8ci f16] = 51840 B
    const int tid  = threadIdx.x;
    const int lane = tid & 63;
    const int wv   = tid >> 6;
    const int b    = blockIdx.z;
    const int z0   = blockIdx.y * 3;
    const int xti  = blockIdx.x % 6;
    const int yti  = blockIdx.x / 6;
    const int x0   = xti * 16, y0 = yti * 16;

    // per-lane B fragments (14 x 16 B, coalesced; table is L2-resident)
    const f16x8* __restrict__ bfp = (const f16x8*)tab;
    f16x8 bfrag[14];
    #pragma unroll
    for (int c = 0; c < 14; ++c)
        bfrag[c] = bfp[(b*14 + c)*64 + lane];

    // stage halo'd tile: 32-B contiguous reads, split to two 16-B LDS halves
    const _Float16* __restrict__ xtb = xt + (size_t)b * VOX * 16;
    for (int s = tid; s < NVX; s += 256) {
        const int lz = s / PLANE;
        const int r1 = s - lz * PLANE;
        const int ly = r1 / LX;
        const int lx = r1 - ly * LX;
        const int zg = z0 - 1 + lz, yg = y0 - 1 + ly, xg = x0 - 1 + lx;
        const bool ok = ((unsigned)zg < 96u) & ((unsigned)yg < 96u) & ((unsigned)xg < 96u);
        const int zc = ok ? zg : 0, yc = ok ? yg : 0, xc = ok ? xg : 0;
        const uint4* __restrict__ p = (const uint4*)(xtb + (size_t)((zc*DD + yc)*DD + xc) * 16);
        uint4 lo = {0,0,0,0}, hi = {0,0,0,0};
        if (ok) { lo = p[0]; hi = p[1]; }
        *(uint4*)&lds[s*16]         = lo;   // ci 0..7
        *(uint4*)&lds[HALFB + s*16] = hi;   // ci 8..15
    }
    __syncthreads();

    // MFMA main loop
    const int q    = lane >> 4;
    const int m    = lane & 15;    // A-row (x offset); also D-col (cout)
    const int pbit = q & 1;
    const int hbit = q >> 1;

    const float* tabf = (const float*)tab;
    const float a_n = tabf[WS_A_F + b*8 + (m & 7)];
    const float d_n = tabf[WS_D_F + b*8 + (m & 7)];

    const int com = hbit*HALFB + m*16;
    const int dA = pbit*16;        // dx parity (A chunks 0..8)
    const int dB = pbit*288;       // dy parity (G chunks 9..11)
    const int dC = pbit*5184;      // dz parity (H12 chunk)

    #define LD_A(p_, dy_)  (*(const f16x8*)&lds[((p_)*PLANE + (yi+(dy_))*LX)*16 + com + dA])
    #define LD_G(p_)       (*(const f16x8*)&lds[((p_)*PLANE + yi*LX + 2)*16 + com + dB])
    #define LD_H12(zi_)    (*(const f16x8*)&lds[((zi_)*PLANE + (yi+2)*LX + 2)*16 + com + dC])
    #define LD_H13(zi_)    (*(const f16x8*)&lds[(((zi_)+2)*PLANE + (yi+2)*LX + 2)*16 + com])

    #pragma unroll
    for (int yi4 = 0; yi4 < 4; ++yi4) {
        const int yi = wv*4 + yi4;

        f16x8 A[3][3], G[3];
        #pragma unroll
        for (int dy = 0; dy < 3; ++dy) { A[0][dy] = LD_A(0, dy); A[1][dy] = LD_A(1, dy); }
        G[0] = LD_G(0); G[1] = LD_G(1);

        #pragma unroll
        for (int zi = 0; zi < 3; ++zi) {
            #pragma unroll
            for (int dy = 0; dy < 3; ++dy) A[2][dy] = LD_A(zi+2, dy);
            G[2] = LD_G(zi+2);
            const f16x8 H12v = LD_H12(zi);
            const f16x8 H13v = LD_H13(zi);   // odd-parity lanes alias (B=0 there)

            f32x4 acc0 = {0.f,0.f,0.f,0.f}, acc1 = {0.f,0.f,0.f,0.f};
            acc0 = __builtin_amdgcn_mfma_f32_16x16x32_f16(A[0][0], bfrag[0],  acc0, 0,0,0);
            acc1 = __builtin_amdgcn_mfma_f32_16x16x32_f16(A[0][1], bfrag[1],  acc1, 0,0,0);
            acc0 = __builtin_amdgcn_mfma_f32_16x16x32_f16(A[0][2], bfrag[2],  acc0, 0,0,0);
            acc1 = __builtin_amdgcn_mfma_f32_16x16x32_f16(A[1][0], bfrag[3],  acc1, 0,0,0);
            acc0 = __builtin_amdgcn_mfma_f32_16x16x32_f16(A[1][1], bfrag[4],  acc0, 0,0,0);
            acc1 = __builtin_amdgcn_mfma_f32_16x16x32_f16(A[1][2], bfrag[5],  acc1, 0,0,0);
            acc0 = __builtin_amdgcn_mfma_f32_16x16x32_f16(A[2][0], bfrag[6],  acc0, 0,0,0);
            acc1 = __builtin_amdgcn_mfma_f32_16x16x32_f16(A[2][1], bfrag[7],  acc1, 0,0,0);
            acc0 = __builtin_amdgcn_mfma_f32_16x16x32_f16(A[2][2], bfrag[8],  acc0, 0,0,0);
            acc1 = __builtin_amdgcn_mfma_f32_16x16x32_f16(G[0],    bfrag[9],  acc1, 0,0,0);
            acc0 = __builtin_amdgcn_mfma_f32_16x16x32_f16(G[1],    bfrag[10], acc0, 0,0,0);
            acc1 = __builtin_amdgcn_mfma_f32_16x16x32_f16(G[2],    bfrag[11], acc1, 0,0,0);
            acc0 = __builtin_amdgcn_mfma_f32_16x16x32_f16(H12v,    bfrag[12], acc0, 0,0,0);
            acc1 = __builtin_amdgcn_mfma_f32_16x16x32_f16(H13v,    bfrag[13], acc1, 0,0,0);

            if (m < 8) {  // D cols 8..15 are padding
                const int zz = z0 + zi, yy = y0 + yi;
                float* __restrict__ op = out + (size_t)(b*COUT + m)*VOX
                                            + (size_t)(zz*DD + yy)*DD + x0 + q*4;
                f32x4 res;
                #pragma unroll
                for (int r = 0; r < 4; ++r) res[r] = fmaf(acc0[r] + acc1[r], a_n, d_n);
                *reinterpret_cast<f32x4*>(op) = res;
            }

            // rotate plane cache
            #pragma unroll
            for (int dy = 0; dy < 3; ++dy) { A[0][dy] = A[1][dy]; A[1][dy] = A[2][dy]; }
            G[0] = G[1]; G[1] = G[2];
        }
    }
    #undef LD_A
    #undef LD_G
    #undef LD_H12
    #undef LD_H13
}

extern "C" void kernel_launch(void* const* d_in, const int* in_sizes, int n_in,
                              void* d_out, int out_size, void* d_ws, size_t ws_size,
                              hipStream_t stream) {
    const float* x    = (const float*)d_in[0];
    const float* text = (const float*)d_in[1];
    const float* wb   = (const float*)d_in[2];
    const float* bb   = (const float*)d_in[3];
    const float* rw1  = (const float*)d_in[4];
    const float* rb1  = (const float*)d_in[5];
    const float* rw2  = (const float*)d_in[6];
    const float* rb2  = (const float*)d_in[7];
    const float* mw1  = (const float*)d_in[8];
    const float* mb1  = (const float*)d_in[9];
    const float* mw2  = (const float*)d_in[10];
    const float* mb2  = (const float*)d_in[11];

    float* out = (float*)d_out;
    _Float16* xt = (_Float16*)d_ws;
    char* tab = (char*)d_ws + XT_BYTES;

    transpose_setup<<<dim3(NTB + 1, NB), 256, 0, stream>>>(
        x, xt, text, wb, bb, rw1, rb1, rw2, rb2, mw1, mb1, mw2, mb2,
        out + OUT_ELEMS, tab);

    conv_mfma<<<dim3(36, 32, NB), 256, 0, stream>>>(xt, tab, out);
}

// Round 6
// 269.939 us; speedup vs baseline: 1.0335x; 1.0335x over previous
//
#include <hip/hip_runtime.h>
#include <math.h>

// Problem constants
#define NB 2
#define CIN 16
#define COUT 8
#define DD 96
#define TDIM 256
#define NE 8
#define VOX (DD*DD*DD)          // 884736
#define OUT_ELEMS (NB*COUT*VOX) // 14155776

// ---- workspace layout ----
// [0, XT_BYTES): xt, f16 channels-last [b][vox][ci16] = 32 B / voxel
// [XT_BYTES, +28672): B-fragment table f16 [b][chunk14][lane64][j8]
// then floats at f32-offset 7168: a[b][co]; 7184: d[b][co]
#define XT_BYTES ((size_t)NB * VOX * 32)
#define WS_A_F 7168
#define WS_D_F 7184

// conv LDS tile: 16x*16y*3z outputs, halo -> 18*18*5 voxels
#define LX 18
#define PLANE (LX*LX)           // 324
#define NVX (PLANE*5)           // 1620
#define HALFB (NVX*16)          // 25920 B per ci-half ([vox][8ci] f16)

#define TV 1024                 // transpose voxels per block (4 per thread)
#define NTB (VOX/TV)            // 864

typedef _Float16 f16x8 __attribute__((ext_vector_type(8)));
typedef float f32x4 __attribute__((ext_vector_type(4)));

// 8-accumulator dot helper: breaks the fmaf dependency chain so 8 loads fly.
#define DOT8(ACC, N, EXPR_X, EXPR_W)                                   \
    float ACC;                                                          \
    {                                                                   \
        float a0=0.f,a1=0.f,a2=0.f,a3=0.f,a4=0.f,a5=0.f,a6=0.f,a7=0.f; \
        for (int k = 0; k < (N); k += 8) {                              \
            { const int kk=k+0; a0 = fmaf(EXPR_X, EXPR_W, a0); }        \
            { const int kk=k+1; a1 = fmaf(EXPR_X, EXPR_W, a1); }        \
            { const int kk=k+2; a2 = fmaf(EXPR_X, EXPR_W, a2); }        \
            { const int kk=k+3; a3 = fmaf(EXPR_X, EXPR_W, a3); }        \
            { const int kk=k+4; a4 = fmaf(EXPR_X, EXPR_W, a4); }        \
            { const int kk=k+5; a5 = fmaf(EXPR_X, EXPR_W, a5); }        \
            { const int kk=k+6; a6 = fmaf(EXPR_X, EXPR_W, a6); }        \
            { const int kk=k+7; a7 = fmaf(EXPR_X, EXPR_W, a7); }        \
        }                                                               \
        ACC = ((a0+a1)+(a2+a3)) + ((a4+a5)+(a6+a7));                    \
    }

// ---------------- fused transpose + setup ----------------
// Grid (NTB+1, NB). Block (0, b) runs the setup path for batch b (dispatched
// FIRST so it overlaps the transpose blocks instead of tailing them).
__global__ __launch_bounds__(256, 4) void transpose_setup(
    const float* __restrict__ x, _Float16* __restrict__ xt,
    const float* __restrict__ text,
    const float* __restrict__ wb,    // [E,COUT,CIN,27]
    const float* __restrict__ bb,    // [E,COUT]
    const float* __restrict__ rw1, const float* __restrict__ rb1,
    const float* __restrict__ rw2, const float* __restrict__ rb2,
    const float* __restrict__ mw1, const float* __restrict__ mb1,
    const float* __restrict__ mw2, const float* __restrict__ mb2,
    float* __restrict__ dout_tail,   // d_out + OUT_ELEMS
    char* __restrict__ tab)          // ws + XT_BYTES
{
    __shared__ float hg[2][64], logits[NE], gpre[COUT], rwv[NE];
    const int t = threadIdx.x;
    const int b = blockIdx.y;

    if (blockIdx.x == 0) {
        // ---------- setup path (one block per batch) ----------
        if (t < 128) {
            const int which = t >> 6, j = t & 63;     // 0=router,1=modulator
            const float* __restrict__ w1 = which ? mw1 : rw1;
            const float* __restrict__ b1 = which ? mb1 : rb1;
            const float* __restrict__ tx = text + b*TDIM;
            DOT8(acc, TDIM, tx[kk], w1[kk*64 + j]);
            acc += b1[j];
            hg[which][j] = (acc >= 0.f) ? acc : 0.1f * acc;
        }
        __syncthreads();
        if (t < NE) {
            DOT8(acc, 64, hg[0][kk], rw2[kk*NE + t]);
            acc += rb2[t];
            logits[t] = acc;
            dout_tail[b*NE + t] = acc;                // router_logits
        } else if (t < 2*NE) {
            const int co = t - NE;
            DOT8(acc, 64, hg[1][kk], mw2[kk*COUT + co]);
            gpre[co] = acc + mb2[co];
        }
        __syncthreads();
        if (t < NE) {
            float mx = logits[0];
            for (int k = 1; k < NE; ++k) mx = fmaxf(mx, logits[k]);
            float s = 0.f;
            for (int k = 0; k < NE; ++k) s += expf(logits[k] - mx);
            const float w = expf(logits[t] - mx) / s;
            rwv[t] = w;
            dout_tail[NB*NE + b*NE + t] = w;          // routing_weights
        }
        __syncthreads();
        if (t < COUT) {
            const float gamma = 1.f / (1.f + expf(-gpre[t]));
            const float a = 1.f + gamma;
            float cb = 0.f;
            for (int e = 0; e < NE; ++e) cb = fmaf(rwv[e], bb[e*COUT + t], cb);
            ((float*)tab)[WS_A_F + b*COUT + t] = a;
            ((float*)tab)[WS_D_F + b*COUT + t] = cb * a;
        }
        // bake per-lane MFMA B-fragments for this batch: r = (c*64 + lane)*8 + j
        for (int r = t; r < 14*64*8; r += 256) {
            const int c  = r >> 9;
            const int l  = (r >> 3) & 63;
            const int j  = r & 7;
            const int q  = l >> 4;
            const int n  = l & 15;       // output column = cout (cols 8..15 zero)
            const int p  = q & 1;        // tap parity within chunk
            const int ci = (q >> 1)*8 + j;
            int tap;
            if (c < 9)        tap = (c/3)*9 + (c%3)*3 + p;
            else if (c < 12)  tap = (c-9)*9 + p*3 + 2;
            else if (c == 12) tap = p*9 + 8;
            else              tap = p ? -1 : 26;
            float v = 0.f;
            if (n < 8 && tap >= 0) {
                for (int e = 0; e < NE; ++e)
                    v = fmaf(rwv[e], wb[((e*COUT + n)*CIN + ci)*27 + tap], v);
            }
            ((_Float16*)tab)[b*7168 + r] = (_Float16)v;
        }
        return;
    }

    // ---------- transpose path: x f32 [b][ci][vox] -> xt f16 [b][vox][ci16] ----------
    // Thread owns 4 consecutive voxels. 16 independent float4 loads (one per ci),
    // register repack, 4 x 32 B contiguous stores.
    const int vbase = (blockIdx.x - 1) * TV + t * 4;
    const float* __restrict__ xb = x + (size_t)b * CIN * VOX + vbase;

    float4 f[CIN];
    #pragma unroll
    for (int ci = 0; ci < CIN; ++ci)
        f[ci] = *(const float4*)(xb + (size_t)ci * VOX);

    _Float16* __restrict__ dst = xt + (size_t)(b*VOX + vbase) * 16;
    #pragma unroll
    for (int k = 0; k < 4; ++k) {
        union { _Float16 h[16]; uint4 u[2]; } o;
        #pragma unroll
        for (int ci = 0; ci < CIN; ++ci) {
            const float* fp = (const float*)&f[ci];
            o.h[ci] = (_Float16)fp[k];
        }
        uint4* __restrict__ d4 = (uint4*)(dst + k*16);
        d4[0] = o.u[0];
        d4[1] = o.u[1];
    }
}

// ---------------- conv: implicit-GEMM f16 MFMA, rolling-plane frag reuse ----------------
// Block = 256 thr (4 waves), tile 16x*16y*3z. Grid = (36, 32, 2).
__global__ __launch_bounds__(256) void conv_mfma(
    const _Float16* __restrict__ xt,   // [b][vox][16] f16
    const char* __restrict__ tab,
    float* __restrict__ out)
{
    __shared__ char lds[2*HALFB];   // [half][vox 1620][8ci f16] = 51840 B
    const int tid  = threadIdx.x;
    const int lane = tid & 63;
    const int wv   = tid >> 6;
    const int b    = blockIdx.z;
    const int z0   = blockIdx.y * 3;
    const int xti  = blockIdx.x % 6;
    const int yti  = blockIdx.x / 6;
    const int x0   = xti * 16, y0 = yti * 16;

    // per-lane B fragments (14 x 16 B, coalesced; table is L2-resident)
    const f16x8* __restrict__ bfp = (const f16x8*)tab;
    f16x8 bfrag[14];
    #pragma unroll
    for (int c = 0; c < 14; ++c)
        bfrag[c] = bfp[(b*14 + c)*64 + lane];

    // stage halo'd tile: 32-B contiguous reads, split to two 16-B LDS halves
    const _Float16* __restrict__ xtb = xt + (size_t)b * VOX * 16;
    for (int s = tid; s < NVX; s += 256) {
        const int lz = s / PLANE;
        const int r1 = s - lz * PLANE;
        const int ly = r1 / LX;
        const int lx = r1 - ly * LX;
        const int zg = z0 - 1 + lz, yg = y0 - 1 + ly, xg = x0 - 1 + lx;
        const bool ok = ((unsigned)zg < 96u) & ((unsigned)yg < 96u) & ((unsigned)xg < 96u);
        const int zc = ok ? zg : 0, yc = ok ? yg : 0, xc = ok ? xg : 0;
        const uint4* __restrict__ p = (const uint4*)(xtb + (size_t)((zc*DD + yc)*DD + xc) * 16);
        uint4 lo = {0,0,0,0}, hi = {0,0,0,0};
        if (ok) { lo = p[0]; hi = p[1]; }
        *(uint4*)&lds[s*16]         = lo;   // ci 0..7
        *(uint4*)&lds[HALFB + s*16] = hi;   // ci 8..15
    }
    __syncthreads();

    // MFMA main loop
    const int q    = lane >> 4;
    const int m    = lane & 15;    // A-row (x offset); also D-col (cout)
    const int pbit = q & 1;
    const int hbit = q >> 1;

    const float* tabf = (const float*)tab;
    const float a_n = tabf[WS_A_F + b*8 + (m & 7)];
    const float d_n = tabf[WS_D_F + b*8 + (m & 7)];

    const int com = hbit*HALFB + m*16;
    const int dA = pbit*16;        // dx parity (A chunks 0..8)
    const int dB = pbit*288;       // dy parity (G chunks 9..11)
    const int dC = pbit*5184;      // dz parity (H12 chunk)

    #define LD_A(p_, dy_)  (*(const f16x8*)&lds[((p_)*PLANE + (yi+(dy_))*LX)*16 + com + dA])
    #define LD_G(p_)       (*(const f16x8*)&lds[((p_)*PLANE + yi*LX + 2)*16 + com + dB])
    #define LD_H12(zi_)    (*(const f16x8*)&lds[((zi_)*PLANE + (yi+2)*LX + 2)*16 + com + dC])
    #define LD_H13(zi_)    (*(const f16x8*)&lds[(((zi_)+2)*PLANE + (yi+2)*LX + 2)*16 + com])

    #pragma unroll
    for (int yi4 = 0; yi4 < 4; ++yi4) {
        const int yi = wv*4 + yi4;

        f16x8 A[3][3], G[3];
        #pragma unroll
        for (int dy = 0; dy < 3; ++dy) { A[0][dy] = LD_A(0, dy); A[1][dy] = LD_A(1, dy); }
        G[0] = LD_G(0); G[1] = LD_G(1);

        #pragma unroll
        for (int zi = 0; zi < 3; ++zi) {
            #pragma unroll
            for (int dy = 0; dy < 3; ++dy) A[2][dy] = LD_A(zi+2, dy);
            G[2] = LD_G(zi+2);
            const f16x8 H12v = LD_H12(zi);
            const f16x8 H13v = LD_H13(zi);   // odd-parity lanes alias (B=0 there)

            f32x4 acc0 = {0.f,0.f,0.f,0.f}, acc1 = {0.f,0.f,0.f,0.f};
            acc0 = __builtin_amdgcn_mfma_f32_16x16x32_f16(A[0][0], bfrag[0],  acc0, 0,0,0);
            acc1 = __builtin_amdgcn_mfma_f32_16x16x32_f16(A[0][1], bfrag[1],  acc1, 0,0,0);
            acc0 = __builtin_amdgcn_mfma_f32_16x16x32_f16(A[0][2], bfrag[2],  acc0, 0,0,0);
            acc1 = __builtin_amdgcn_mfma_f32_16x16x32_f16(A[1][0], bfrag[3],  acc1, 0,0,0);
            acc0 = __builtin_amdgcn_mfma_f32_16x16x32_f16(A[1][1], bfrag[4],  acc0, 0,0,0);
            acc1 = __builtin_amdgcn_mfma_f32_16x16x32_f16(A[1][2], bfrag[5],  acc1, 0,0,0);
            acc0 = __builtin_amdgcn_mfma_f32_16x16x32_f16(A[2][0], bfrag[6],  acc0, 0,0,0);
            acc1 = __builtin_amdgcn_mfma_f32_16x16x32_f16(A[2][1], bfrag[7],  acc1, 0,0,0);
            acc0 = __builtin_amdgcn_mfma_f32_16x16x32_f16(A[2][2], bfrag[8],  acc0, 0,0,0);
            acc1 = __builtin_amdgcn_mfma_f32_16x16x32_f16(G[0],    bfrag[9],  acc1, 0,0,0);
            acc0 = __builtin_amdgcn_mfma_f32_16x16x32_f16(G[1],    bfrag[10], acc0, 0,0,0);
            acc1 = __builtin_amdgcn_mfma_f32_16x16x32_f16(G[2],    bfrag[11], acc1, 0,0,0);
            acc0 = __builtin_amdgcn_mfma_f32_16x16x32_f16(H12v,    bfrag[12], acc0, 0,0,0);
            acc1 = __builtin_amdgcn_mfma_f32_16x16x32_f16(H13v,    bfrag[13], acc1, 0,0,0);

            if (m < 8) {  // D cols 8..15 are padding
                const int zz = z0 + zi, yy = y0 + yi;
                float* __restrict__ op = out + (size_t)(b*COUT + m)*VOX
                                            + (size_t)(zz*DD + yy)*DD + x0 + q*4;
                f32x4 res;
                #pragma unroll
                for (int r = 0; r < 4; ++r) res[r] = fmaf(acc0[r] + acc1[r], a_n, d_n);
                *reinterpret_cast<f32x4*>(op) = res;
            }

            // rotate plane cache
            #pragma unroll
            for (int dy = 0; dy < 3; ++dy) { A[0][dy] = A[1][dy]; A[1][dy] = A[2][dy]; }
            G[0] = G[1]; G[1] = G[2];
        }
    }
    #undef LD_A
    #undef LD_G
    #undef LD_H12
    #undef LD_H13
}

extern "C" void kernel_launch(void* const* d_in, const int* in_sizes, int n_in,
                              void* d_out, int out_size, void* d_ws, size_t ws_size,
                              hipStream_t stream) {
    const float* x    = (const float*)d_in[0];
    const float* text = (const float*)d_in[1];
    const float* wb   = (const float*)d_in[2];
    const float* bb   = (const float*)d_in[3];
    const float* rw1  = (const float*)d_in[4];
    const float* rb1  = (const float*)d_in[5];
    const float* rw2  = (const float*)d_in[6];
    const float* rb2  = (const float*)d_in[7];
    const float* mw1  = (const float*)d_in[8];
    const float* mb1  = (const float*)d_in[9];
    const float* mw2  = (const float*)d_in[10];
    const float* mb2  = (const float*)d_in[11];

    float* out = (float*)d_out;
    _Float16* xt = (_Float16*)d_ws;
    char* tab = (char*)d_ws + XT_BYTES;

    transpose_setup<<<dim3(NTB + 1, NB), 256, 0, stream>>>(
        x, xt, text, wb, bb, rw1, rb1, rw2, rb2, mw1, mb1, mw2, mb2,
        out + OUT_ELEMS, tab);

    conv_mfma<<<dim3(36, 32, NB), 256, 0, stream>>>(xt, tab, out);
}